// Round 1
// 379.447 us; speedup vs baseline: 1.1381x; 1.1381x over previous
//
#include <hip/hip_runtime.h>
#include <math.h>

// WaveletDenoiser — R3: full per-row fusion.
// One workgroup (512 thr) per row; the entire 4-level DWT -> exact median
// radix-select -> soft-threshold -> 4-level IDWT pipeline runs LDS-resident.
// HBM traffic drops from ~1.07 GB (9 dispatches) to 268 MB (read x + write out).
//
// LDS (floats):
//   a2[4112] d2[4112] a3[2064] d3[2064] a4[1040] d4[1040]   (level 2..4 coeffs,
//                                                            rec3/rec2 overwrite a3/a2)
//   a1[8200] (later rec1)   d1[8200]
//   + hist[256], scn[256], sP, sK            total ~125.4 KB  -> 1 block/CU
//
// DWT: thread v computes 4 output pairs t=4v..4v+3 from src[8v-16 .. 8v+7]
//   (24-float window, 6x float4 reads, 3x read amplification vs 5x at P=2).
//   Level 1 reads x directly from global (L1 absorbs the overlap; no X staging).
// IDWT: unchanged math from R2 (8 outputs/thread, 3x float4 per operand).
// Median: 4-pass 8-bit radix select on |d1| (rank 4099 of 8199); 256-bin scan
//   done by wave 0 via __shfl_up (4 barriers/pass instead of 16).
// Numerically bit-identical to R2 (same per-output FMA order).

constexpr float HF[16] = {
  0.05441584224308161f,     0.3128715909144659f,     0.6756307362980128f,
  0.5853546836548691f,     -0.015829105256023893f,  -0.2840155429624281f,
  0.00047248457399797254f,  0.128747426620186f,     -0.01736930100202211f,
 -0.04408825393106472f,     0.013981027917015516f,   0.008746094047015655f,
 -0.00487035299301066f,    -0.0003917403729959771f,  0.0006754494059985568f,
 -0.00011747678400228192f
};

constexpr int L0 = 16384;
constexpr int T1 = 8199, T2 = 4107, T3 = 2061;          // T4 = 1038
constexpr int S1 = 8200, S2 = 4112, S3 = 2064, S4 = 1040;
constexpr int NT = 512;

// LDS layout (float offsets); all offsets multiples of 4 floats (16B aligned)
constexpr int O_A2 = 0;
constexpr int O_D2 = O_A2 + S2;     // 4112
constexpr int O_A3 = O_D2 + S2;     // 8224
constexpr int O_D3 = O_A3 + S3;     // 10288
constexpr int O_A4 = O_D3 + S3;     // 12352
constexpr int O_D4 = O_A4 + S4;     // 13392
constexpr int O_A1 = O_D4 + S4;     // 14432
constexpr int O_D1 = O_A1 + S1;     // 22632
constexpr int LDSF = O_D1 + S1;     // 30832 floats = 123,328 B

// Forward DWT: thread v -> pairs t = 4v..4v+3; src index 2t-14+k = (8v-16)+(2p+2+k).
__device__ __forceinline__ void dwt_stage(const float* __restrict__ src, int Lin,
                                          float* __restrict__ ca,
                                          float* __restrict__ cd,
                                          int Sout, int tid) {
  const int V = Sout >> 2;
  for (int v = tid; v < V; v += NT) {
    float w[24];
    const int base = 8 * v - 16;
    if (v >= 2 && 8 * v + 7 < Lin) {
      const float4* sv = reinterpret_cast<const float4*>(src + base);
#pragma unroll
      for (int q = 0; q < 6; ++q) {
        const float4 t4 = sv[q];
        w[4 * q + 0] = t4.x; w[4 * q + 1] = t4.y;
        w[4 * q + 2] = t4.z; w[4 * q + 3] = t4.w;
      }
    } else {
#pragma unroll
      for (int k = 0; k < 24; ++k) {
        int g = base + k;
        if (g < 0) g = -1 - g;
        else if (g >= Lin) g = 2 * Lin - 1 - g;
        w[k] = src[g];
      }
    }
    float a[4] = {0.f, 0.f, 0.f, 0.f};
    float d[4] = {0.f, 0.f, 0.f, 0.f};
#pragma unroll
    for (int k = 0; k < 16; ++k) {
      const float hk = HF[k];
      const float gk = (k & 1) ? -HF[15 - k] : HF[15 - k];
#pragma unroll
      for (int p = 0; p < 4; ++p) {
        a[p] = fmaf(w[2 * p + 2 + k], hk, a[p]);
        d[p] = fmaf(w[2 * p + 2 + k], gk, d[p]);
      }
    }
    *reinterpret_cast<float4*>(ca + 4 * v) = make_float4(a[0], a[1], a[2], a[3]);
    *reinterpret_cast<float4*>(cd + 4 * v) = make_float4(d[0], d[1], d[2], d[3]);
  }
}

// Inverse DWT with on-the-fly soft-threshold of cd. 8 outputs t=8u..8u+7.
__device__ __forceinline__ void idwt_stage(const float* __restrict__ ca,
                                           const float* __restrict__ cd,
                                           float th,
                                           float* __restrict__ outp,
                                           int Sout, int tid) {
  const int U = Sout >> 3;
  for (int u = tid; u < U; u += NT) {
    const float4* av = reinterpret_cast<const float4*>(ca + 4 * u);
    const float4* dv = reinterpret_cast<const float4*>(cd + 4 * u);
    const float4 a0 = av[0], a1 = av[1], a2 = av[2];
    const float4 e0 = dv[0], e1 = dv[1], e2 = dv[2];
    const float A[12]  = {a0.x, a0.y, a0.z, a0.w, a1.x, a1.y, a1.z, a1.w,
                          a2.x, a2.y, a2.z, a2.w};
    const float Dr[12] = {e0.x, e0.y, e0.z, e0.w, e1.x, e1.y, e1.z, e1.w,
                          e2.x, e2.y, e2.z, e2.w};
    float Ds[12];
#pragma unroll
    for (int j = 0; j < 12; ++j) {
      const float dd = Dr[j];
      const float mag = fabsf(dd) - th;
      Ds[j] = (mag > 0.f) ? copysignf(mag, dd) : 0.f;
    }
    float o[8];
#pragma unroll
    for (int e = 0; e < 8; ++e) {
      const int b = e >> 1;
      float acc = 0.f;
#pragma unroll
      for (int j = 0; j < 8; ++j) {
        const float cA = (e & 1) ? HF[15 - 2 * j] : HF[14 - 2 * j];
        const float cD = (e & 1) ? -HF[2 * j]     : HF[2 * j + 1];
        acc = fmaf(A[b + j], cA, acc);
        acc = fmaf(Ds[b + j], cD, acc);
      }
      o[e] = acc;
    }
    float4* ov = reinterpret_cast<float4*>(outp + 8 * u);
    ov[0] = make_float4(o[0], o[1], o[2], o[3]);
    ov[1] = make_float4(o[4], o[5], o[6], o[7]);
  }
}

__global__ __launch_bounds__(NT) void fused_k(const float* __restrict__ x,
                                              float* __restrict__ out,
                                              float scale) {
  __shared__ float S[LDSF];
  __shared__ unsigned hist[256];
  __shared__ unsigned scn[256];
  __shared__ unsigned sP, sK;

  const int tid = threadIdx.x;
  const int row = blockIdx.x;
  const float* xr = x + (size_t)row * L0;

  // Forward transform chain (level 1 reads global directly)
  dwt_stage(xr, L0, S + O_A1, S + O_D1, S1, tid);
  __syncthreads();
  dwt_stage(S + O_A1, T1, S + O_A2, S + O_D2, S2, tid);
  __syncthreads();
  dwt_stage(S + O_A2, T2, S + O_A3, S + O_D3, S3, tid);
  __syncthreads();
  dwt_stage(S + O_A3, T3, S + O_A4, S + O_D4, S4, tid);
  if (tid == 0) { sP = 0u; sK = 4099u; }   // rank (T1-1)/2 of T1=8199
  __syncthreads();                          // also covers dwt4 completion

  // Exact median of |d1| via 4-pass 8-bit radix select (order-isomorphic bits)
  const float* d1 = S + O_D1;
  for (int shift = 24; shift >= 0; shift -= 8) {
    if (tid < 256) hist[tid] = 0u;
    __syncthreads();
    const unsigned pref = sP;
    const unsigned kk   = sK;
    for (int i = tid; i < T1; i += NT) {
      const unsigned v = __float_as_uint(fabsf(d1[i]));
      if ((unsigned)(((unsigned long long)v) >> (shift + 8)) == pref)
        atomicAdd(&hist[(v >> shift) & 255u], 1u);
    }
    __syncthreads();
    if (tid < 64) {   // wave 0: 256-bin inclusive scan, 4 bins/lane + shfl scan
      const unsigned b0 = hist[4 * tid + 0], b1 = hist[4 * tid + 1];
      const unsigned b2 = hist[4 * tid + 2], b3 = hist[4 * tid + 3];
      const unsigned tot = b0 + b1 + b2 + b3;
      unsigned s = tot;
#pragma unroll
      for (int off = 1; off < 64; off <<= 1) {
        const unsigned tv = __shfl_up(s, off, 64);
        if (tid >= off) s += tv;
      }
      unsigned run = s - tot;
      run += b0; scn[4 * tid + 0] = run;
      run += b1; scn[4 * tid + 1] = run;
      run += b2; scn[4 * tid + 2] = run;
      run += b3; scn[4 * tid + 3] = run;
    }
    __syncthreads();
    if (tid < 256) {
      const unsigned incl = scn[tid];
      const unsigned excl = incl - hist[tid];
      if (kk >= excl && kk < incl) {
        sP = (pref << 8) | (unsigned)tid;
        sK = kk - excl;
      }
    }
    __syncthreads();
  }
  const float th = __uint_as_float(sP) * scale;

  // Inverse chain: rec3 -> a3 slot, rec2 -> a2 slot, rec1 -> a1 slot, final -> global
  idwt_stage(S + O_A4, S + O_D4, th, S + O_A3, S3, tid);
  __syncthreads();
  idwt_stage(S + O_A3, S + O_D3, th, S + O_A2, S2, tid);
  __syncthreads();
  idwt_stage(S + O_A2, S + O_D2, th, S + O_A1, S1, tid);
  __syncthreads();
  idwt_stage(S + O_A1, S + O_D1, th, out + (size_t)row * L0, L0, tid);
}

extern "C" void kernel_launch(void* const* d_in, const int* in_sizes, int n_in,
                              void* d_out, int out_size, void* d_ws, size_t ws_size,
                              hipStream_t stream) {
  (void)n_in; (void)out_size; (void)d_ws; (void)ws_size;
  const float* x = (const float*)d_in[0];
  float* out = (float*)d_out;
  const int rows = in_sizes[0] / L0;   // 2048
  const float scale = (float)(sqrt(2.0 * log((double)L0)) / 0.6745);
  fused_k<<<dim3((unsigned)rows), dim3(NT), 0, stream>>>(x, out, scale);
}

// Round 2
// 357.682 us; speedup vs baseline: 1.2073x; 1.0608x over previous
//
#include <hip/hip_runtime.h>
#include <math.h>

// WaveletDenoiser — R4: fused per-row pipeline, NT=1024, LDS XOR-swizzle.
//
// R3 post-mortem: latency-bound (VALUBusy 28%, HBM 3.6%, occupancy 22.8% =
// 2 waves/SIMD), plus 1.2e7 LDS bank-conflict cycles from the DWT's 32B-stride
// ds_read_b128 window loads (lanes 0,4,8.. share a 4-bank group).
// R4: (a) NT=1024 -> 4 waves/SIMD, halves per-level iteration counts;
//     (b) XOR swizzle i ^= ((i>>5)&3)<<2 on every LDS coefficient access
//         (write+read consistent; flips byte bits [5:4] only, so float4
//         alignment is preserved and each 16-float block is permuted in-place;
//         median histogram reads a permutation of the same value set);
//     (c) median: double-buffered hist, clear folded into scan phase
//         (3 barriers/pass instead of 4).
// FMA order per output unchanged -> bit-identical results to R3.

constexpr float HF[16] = {
  0.05441584224308161f,     0.3128715909144659f,     0.6756307362980128f,
  0.5853546836548691f,     -0.015829105256023893f,  -0.2840155429624281f,
  0.00047248457399797254f,  0.128747426620186f,     -0.01736930100202211f,
 -0.04408825393106472f,     0.013981027917015516f,   0.008746094047015655f,
 -0.00487035299301066f,    -0.0003917403729959771f,  0.0006754494059985568f,
 -0.00011747678400228192f
};

constexpr int L0 = 16384;
constexpr int T1 = 8199, T2 = 4107, T3 = 2061;          // T4 = 1038
constexpr int S1 = 8200, S2 = 4112, S3 = 2064, S4 = 1040;
constexpr int NT = 1024;

// LDS layout (float offsets), each base a multiple of 32 floats so the
// swizzle's 32-float blocks line up with array starts.
constexpr int O_A2 = 0;
constexpr int O_D2 = O_A2 + 4128;   // S2 padded 4112->4128
constexpr int O_A3 = O_D2 + 4128;   // 8256
constexpr int O_D3 = O_A3 + 2080;   // S3 2064->2080 ; 10336
constexpr int O_A4 = O_D3 + 2080;   // 12416
constexpr int O_D4 = O_A4 + 1056;   // S4 1040->1056 ; 13472
constexpr int O_A1 = O_D4 + 1056;   // 14528
constexpr int O_D1 = O_A1 + 8224;   // S1 8200->8224 ; 22752
constexpr int LDSF = O_D1 + 8224;   // 30976 floats = 123,904 B

// Bank-decorrelating swizzle: permutes 4-float chunks within each 32-float
// (128B) block. Bits [1:0] of the float index are untouched.
__device__ __forceinline__ int swz(int i) { return i ^ (((i >> 5) & 3) << 2); }

// Forward DWT: thread v -> output pairs t = 4v..4v+3 from src[8v-16 .. 8v+7].
template<bool SSWZ>
__device__ __forceinline__ void dwt_stage(const float* __restrict__ src, int Lin,
                                          float* __restrict__ ca,
                                          float* __restrict__ cd,
                                          int Sout, int tid) {
  const int V = Sout >> 2;
  for (int v = tid; v < V; v += NT) {
    float w[24];
    const int base = 8 * v - 16;
    if (v >= 2 && 8 * v + 7 < Lin) {
#pragma unroll
      for (int q = 0; q < 6; ++q) {
        const int idx = SSWZ ? swz(base + 4 * q) : (base + 4 * q);
        const float4 t4 = *reinterpret_cast<const float4*>(src + idx);
        w[4 * q + 0] = t4.x; w[4 * q + 1] = t4.y;
        w[4 * q + 2] = t4.z; w[4 * q + 3] = t4.w;
      }
    } else {
#pragma unroll
      for (int k = 0; k < 24; ++k) {
        int g = base + k;
        if (g < 0) g = -1 - g;
        else if (g >= Lin) g = 2 * Lin - 1 - g;
        w[k] = src[SSWZ ? swz(g) : g];
      }
    }
    float a[4] = {0.f, 0.f, 0.f, 0.f};
    float d[4] = {0.f, 0.f, 0.f, 0.f};
#pragma unroll
    for (int k = 0; k < 16; ++k) {
      const float hk = HF[k];
      const float gk = (k & 1) ? -HF[15 - k] : HF[15 - k];
#pragma unroll
      for (int p = 0; p < 4; ++p) {
        a[p] = fmaf(w[2 * p + 2 + k], hk, a[p]);
        d[p] = fmaf(w[2 * p + 2 + k], gk, d[p]);
      }
    }
    *reinterpret_cast<float4*>(ca + swz(4 * v)) = make_float4(a[0], a[1], a[2], a[3]);
    *reinterpret_cast<float4*>(cd + swz(4 * v)) = make_float4(d[0], d[1], d[2], d[3]);
  }
}

// Inverse DWT with on-the-fly soft-threshold. 8 outputs t=8u..8u+7.
// Sources are always swizzled LDS; DSWZ selects swizzled-LDS vs linear-global dst.
template<bool DSWZ>
__device__ __forceinline__ void idwt_stage(const float* __restrict__ ca,
                                           const float* __restrict__ cd,
                                           float th,
                                           float* __restrict__ outp,
                                           int Sout, int tid) {
  const int U = Sout >> 3;
  for (int u = tid; u < U; u += NT) {
    const float4 a0 = *reinterpret_cast<const float4*>(ca + swz(4 * u));
    const float4 a1 = *reinterpret_cast<const float4*>(ca + swz(4 * u + 4));
    const float4 a2 = *reinterpret_cast<const float4*>(ca + swz(4 * u + 8));
    const float4 e0 = *reinterpret_cast<const float4*>(cd + swz(4 * u));
    const float4 e1 = *reinterpret_cast<const float4*>(cd + swz(4 * u + 4));
    const float4 e2 = *reinterpret_cast<const float4*>(cd + swz(4 * u + 8));
    const float A[12]  = {a0.x, a0.y, a0.z, a0.w, a1.x, a1.y, a1.z, a1.w,
                          a2.x, a2.y, a2.z, a2.w};
    const float Dr[12] = {e0.x, e0.y, e0.z, e0.w, e1.x, e1.y, e1.z, e1.w,
                          e2.x, e2.y, e2.z, e2.w};
    float Ds[12];
#pragma unroll
    for (int j = 0; j < 12; ++j) {
      const float dd = Dr[j];
      const float mag = fabsf(dd) - th;
      Ds[j] = (mag > 0.f) ? copysignf(mag, dd) : 0.f;
    }
    float o[8];
#pragma unroll
    for (int e = 0; e < 8; ++e) {
      const int b = e >> 1;
      float acc = 0.f;
#pragma unroll
      for (int j = 0; j < 8; ++j) {
        const float cA = (e & 1) ? HF[15 - 2 * j] : HF[14 - 2 * j];
        const float cD = (e & 1) ? -HF[2 * j]     : HF[2 * j + 1];
        acc = fmaf(A[b + j], cA, acc);
        acc = fmaf(Ds[b + j], cD, acc);
      }
      o[e] = acc;
    }
    if (DSWZ) {
      *reinterpret_cast<float4*>(outp + swz(8 * u))     = make_float4(o[0], o[1], o[2], o[3]);
      *reinterpret_cast<float4*>(outp + swz(8 * u + 4)) = make_float4(o[4], o[5], o[6], o[7]);
    } else {
      float4* ov = reinterpret_cast<float4*>(outp + 8 * u);
      ov[0] = make_float4(o[0], o[1], o[2], o[3]);
      ov[1] = make_float4(o[4], o[5], o[6], o[7]);
    }
  }
}

__global__ __launch_bounds__(NT) void fused_k(const float* __restrict__ x,
                                              float* __restrict__ out,
                                              float scale) {
  __shared__ float S[LDSF];
  __shared__ unsigned hist[2][256];
  __shared__ unsigned scn[256];
  __shared__ unsigned sP, sK;

  const int tid = threadIdx.x;
  const int row = blockIdx.x;
  const float* xr = x + (size_t)row * L0;

  // Forward chain (level 1 reads global directly; L1/L3 absorb window overlap)
  dwt_stage<false>(xr, L0, S + O_A1, S + O_D1, S1, tid);
  __syncthreads();
  dwt_stage<true>(S + O_A1, T1, S + O_A2, S + O_D2, S2, tid);
  __syncthreads();
  dwt_stage<true>(S + O_A2, T2, S + O_A3, S + O_D3, S3, tid);
  __syncthreads();
  dwt_stage<true>(S + O_A3, T3, S + O_A4, S + O_D4, S4, tid);
  if (tid < 256) hist[0][tid] = 0u;
  if (tid == 0) { sP = 0u; sK = 4099u; }    // rank (T1-1)/2 of T1=8199
  __syncthreads();                           // also covers dwt4 completion

  // Exact median of |d1|: 4-pass 8-bit radix select (bits order-isomorphic
  // to non-negative floats). hist double-buffered: pass p uses hist[p&1],
  // clears hist[(p+1)&1] during the scan phase.
  const float* d1 = S + O_D1;
  for (int pass = 0; pass < 4; ++pass) {
    const int shift = 24 - 8 * pass;
    const unsigned pref = sP;
    const unsigned kk   = sK;
    unsigned* h = hist[pass & 1];
    for (int i = tid; i < T1; i += NT) {
      const unsigned v = __float_as_uint(fabsf(d1[swz(i)]));
      if ((unsigned)(((unsigned long long)v) >> (shift + 8)) == pref)
        atomicAdd(&h[(v >> shift) & 255u], 1u);
    }
    __syncthreads();
    if (tid < 64) {   // wave 0: 256-bin inclusive scan, 4 bins/lane + shfl scan
      const unsigned b0 = h[4 * tid + 0], b1 = h[4 * tid + 1];
      const unsigned b2 = h[4 * tid + 2], b3 = h[4 * tid + 3];
      const unsigned tot = b0 + b1 + b2 + b3;
      unsigned s = tot;
#pragma unroll
      for (int off = 1; off < 64; off <<= 1) {
        const unsigned tv = __shfl_up(s, off, 64);
        if (tid >= off) s += tv;
      }
      unsigned run = s - tot;
      run += b0; scn[4 * tid + 0] = run;
      run += b1; scn[4 * tid + 1] = run;
      run += b2; scn[4 * tid + 2] = run;
      run += b3; scn[4 * tid + 3] = run;
    } else if (tid >= 256 && tid < 512) {
      hist[(pass + 1) & 1][tid - 256] = 0u;
    }
    __syncthreads();
    if (tid < 256) {
      const unsigned incl = scn[tid];
      const unsigned excl = incl - h[tid];
      if (kk >= excl && kk < incl) {    // exactly one bin matches
        sP = (pref << 8) | (unsigned)tid;
        sK = kk - excl;
      }
    }
    __syncthreads();
  }
  const float th = __uint_as_float(sP) * scale;

  // Inverse chain: rec3 -> a3 slot, rec2 -> a2 slot, rec1 -> a1 slot, final -> out
  idwt_stage<true>(S + O_A4, S + O_D4, th, S + O_A3, S3, tid);
  __syncthreads();
  idwt_stage<true>(S + O_A3, S + O_D3, th, S + O_A2, S2, tid);
  __syncthreads();
  idwt_stage<true>(S + O_A2, S + O_D2, th, S + O_A1, S1, tid);
  __syncthreads();
  idwt_stage<false>(S + O_A1, S + O_D1, th, out + (size_t)row * L0, L0, tid);
}

extern "C" void kernel_launch(void* const* d_in, const int* in_sizes, int n_in,
                              void* d_out, int out_size, void* d_ws, size_t ws_size,
                              hipStream_t stream) {
  (void)n_in; (void)out_size; (void)d_ws; (void)ws_size;
  const float* x = (const float*)d_in[0];
  float* out = (float*)d_out;
  const int rows = in_sizes[0] / L0;   // 2048
  const float scale = (float)(sqrt(2.0 * log((double)L0)) / 0.6745);
  fused_k<<<dim3((unsigned)rows), dim3(NT), 0, stream>>>(x, out, scale);
}